// Round 1
// baseline (1109.054 us; speedup 1.0000x reference)
//
#include <hip/hip_runtime.h>
#include <hip/hip_bf16.h>

#define PI_F 3.14159265358979323846f

static inline size_t align256(size_t x) { return (x + 255) & ~size_t(255); }

// ---------------- CSR build ----------------

__global__ void hist_kernel(const int* __restrict__ dst, int* __restrict__ deg, int E) {
    int e = blockIdx.x * blockDim.x + threadIdx.x;
    if (e < E) atomicAdd(&deg[dst[e]], 1);
}

// block scans 1024 elements; also emits dinv = rsqrt(deg+1) (self-loop included)
__global__ void scan1_kernel(const int* __restrict__ deg, int* __restrict__ offs,
                             int* __restrict__ bsum, float* __restrict__ dinv, int n) {
    __shared__ int s[1024];
    int base = blockIdx.x * 1024;
    for (int r = 0; r < 4; r++) {
        int i = threadIdx.x + r * 256;
        int idx = base + i;
        int v = (idx < n) ? deg[idx] : 0;
        s[i] = v;
        if (idx < n) dinv[idx] = rsqrtf((float)(v + 1));
    }
    __syncthreads();
    for (int off = 1; off < 1024; off <<= 1) {
        int vals[4];
        for (int r = 0; r < 4; r++) {
            int i = threadIdx.x + r * 256;
            vals[r] = (i >= off) ? s[i - off] : 0;
        }
        __syncthreads();
        for (int r = 0; r < 4; r++) {
            int i = threadIdx.x + r * 256;
            s[i] += vals[r];
        }
        __syncthreads();
    }
    for (int r = 0; r < 4; r++) {
        int i = threadIdx.x + r * 256;
        int idx = base + i;
        if (idx < n) offs[idx] = (i == 0) ? 0 : s[i - 1];
    }
    if (threadIdx.x == 0) bsum[blockIdx.x] = s[1023];
}

__global__ void scan2_kernel(int* __restrict__ bsum, int nb) {
    __shared__ int s[256];
    int i = threadIdx.x;
    s[i] = (i < nb) ? bsum[i] : 0;
    __syncthreads();
    for (int off = 1; off < 256; off <<= 1) {
        int v = (i >= off) ? s[i - off] : 0;
        __syncthreads();
        s[i] += v;
        __syncthreads();
    }
    if (i < nb) bsum[i] = (i == 0) ? 0 : s[i - 1];
}

__global__ void scan3_kernel(int* __restrict__ offs, const int* __restrict__ bsum, int n, int E) {
    int i = blockIdx.x * blockDim.x + threadIdx.x;
    if (i < n) offs[i] += bsum[i >> 10];
    if (i == 0) offs[n] = E;
}

__global__ void fill_kernel(const int* __restrict__ src, const int* __restrict__ dst,
                            int* __restrict__ pos, int* __restrict__ csr_src, int E) {
    int e = blockIdx.x * blockDim.x + threadIdx.x;
    if (e < E) {
        int d = dst[e];
        int p = atomicAdd(&pos[d], 1);
        csr_src[p] = src[e];
    }
}

// ---------------- GCN layers ----------------

// layer1: u[i][f] = x[i] * dinv[i] * W1[f]   (W1 is [1,32])
__global__ void l1_kernel(const float* __restrict__ x, const float* __restrict__ W1,
                          const float* __restrict__ dinv, float* __restrict__ u, int n) {
    int t = blockIdx.x * blockDim.x + threadIdx.x;
    int node = t >> 5, f = t & 31;
    if (node < n) u[t] = x[node] * dinv[node] * W1[f];
}

// u[i][f] = dinv[i] * sum_k h[i][k]*W[k][f]   (32 lanes per node, W in LDS)
__global__ void gemm_scale_kernel(const float* __restrict__ h, const float* __restrict__ W,
                                  const float* __restrict__ dinv, float* __restrict__ u, int n) {
    __shared__ float sW[1024];
    for (int i = threadIdx.x; i < 1024; i += 256) sW[i] = W[i];
    __syncthreads();
    int t = blockIdx.x * 256 + threadIdx.x;
    int node = t >> 5;
    int lane = threadIdx.x & 63;
    int f = lane & 31, base = lane & 32;
    if (node >= n) return;
    float hv = h[node * 32 + f];
    float acc = 0.f;
#pragma unroll
    for (int k = 0; k < 32; k++) {
        acc += __shfl(hv, base | k, 64) * sW[k * 32 + f];
    }
    u[node * 32 + f] = acc * dinv[node];
}

// h_out[d][f] = relu(dinv[d]*(sum_{src in N(d)} u[src][f] + u[d][f]) + b[f])
// one 64-lane wave per node: halves split the edge list, 32 lanes = features
__global__ void agg_kernel(const float* __restrict__ u, const int* __restrict__ offs,
                           const int* __restrict__ csr_src, const float* __restrict__ dinv,
                           const float* __restrict__ b, float* __restrict__ hout, int n) {
    int t = blockIdx.x * 256 + threadIdx.x;
    int d = t >> 6;
    int lane = threadIdx.x & 63;
    int f = lane & 31, half = lane >> 5;
    if (d >= n) return;
    int e0 = offs[d], e1 = offs[d + 1];
    float acc = 0.f;
    for (int j = e0 + half; j < e1; j += 2) {
        int s = csr_src[j];
        acc += u[s * 32 + f];
    }
    acc += __shfl_xor(acc, 32, 64);
    if (half == 0) {
        float v = dinv[d] * (acc + u[d * 32 + f]) + b[f];
        hout[d * 32 + f] = fmaxf(v, 0.f);
    }
}

// ---------------- heads ----------------

__global__ void theta_kernel(const float* __restrict__ h, const float* __restrict__ Wt1,
                             const float* __restrict__ bt1, const float* __restrict__ Wt2,
                             const float* __restrict__ bt2, float* __restrict__ theta, int n) {
    __shared__ float sW[1024];
    __shared__ float sb[32];
    __shared__ float sw2[32];
    for (int i = threadIdx.x; i < 1024; i += 256) sW[i] = Wt1[i];
    if (threadIdx.x < 32) { sb[threadIdx.x] = bt1[threadIdx.x]; sw2[threadIdx.x] = Wt2[threadIdx.x]; }
    __syncthreads();
    int t = blockIdx.x * 256 + threadIdx.x;
    int node = t >> 5;
    int lane = threadIdx.x & 63;
    int f = lane & 31, base = lane & 32;
    if (node >= n) return;
    float hv = h[node * 32 + f];
    float a = sb[f];
#pragma unroll
    for (int k = 0; k < 32; k++) a += __shfl(hv, base | k, 64) * sW[k * 32 + f];
    a = fmaxf(a, 0.f) * sw2[f];
    a += __shfl_xor(a, 1, 64);
    a += __shfl_xor(a, 2, 64);
    a += __shfl_xor(a, 4, 64);
    a += __shfl_xor(a, 8, 64);
    a += __shfl_xor(a, 16, 64);
    if (f == 0) {
        float s = a + bt2[0];
        theta[node] = PI_F / (1.f + __expf(-s));
    }
}

// sorted-batch run-length pooling: 8 sub-chunks of 128 nodes per block, 32 lanes = features
__global__ void pool_kernel(const float* __restrict__ h, const int* __restrict__ batch,
                            float* __restrict__ gsum, float* __restrict__ gcnt, int n) {
    int f = threadIdx.x & 31;
    int sub = threadIdx.x >> 5;
    int start = blockIdx.x * 1024 + sub * 128;
    int end = min(start + 128, n);
    if (start >= end) return;
    int curg = batch[start];
    float acc = 0.f;
    int cnt = 0;
    for (int i = start; i < end; i++) {
        int g = batch[i];
        if (g != curg) {
            atomicAdd(&gsum[curg * 32 + f], acc);
            if (f == 0) atomicAdd(&gcnt[curg], (float)cnt);
            acc = 0.f; cnt = 0; curg = g;
        }
        acc += h[i * 32 + f];
        cnt++;
    }
    atomicAdd(&gsum[curg * 32 + f], acc);
    if (f == 0) atomicAdd(&gcnt[curg], (float)cnt);
}

__global__ void bg_kernel(const float* __restrict__ gsum, const float* __restrict__ gcnt,
                          const float* __restrict__ Wg1, const float* __restrict__ bg1,
                          const float* __restrict__ Wg2, const float* __restrict__ bg2,
                          float* __restrict__ out, int G) {
    __shared__ float sW[1024];
    for (int i = threadIdx.x; i < 1024; i += 256) sW[i] = Wg1[i];
    __syncthreads();
    int t = blockIdx.x * 256 + threadIdx.x;
    int g = t >> 5;
    int lane = threadIdx.x & 63;
    int f = lane & 31, base = lane & 32;
    if (g >= G) return;
    float cnt = fmaxf(gcnt[g], 1.f);
    float hv = gsum[g * 32 + f] / cnt;
    float a = bg1[f];
#pragma unroll
    for (int k = 0; k < 32; k++) a += __shfl(hv, base | k, 64) * sW[k * 32 + f];
    a = fmaxf(a, 0.f);
    float p0 = a * Wg2[f * 2 + 0];
    float p1 = a * Wg2[f * 2 + 1];
    for (int m = 1; m < 32; m <<= 1) {
        p0 += __shfl_xor(p0, m, 64);
        p1 += __shfl_xor(p1, m, 64);
    }
    if (f == 0) {
        out[g * 2 + 0] = 2.f * PI_F / (1.f + __expf(-(p0 + bg2[0])));
        out[g * 2 + 1] = 2.f * PI_F / (1.f + __expf(-(p1 + bg2[1])));
    }
}

// ---------------- launch ----------------

extern "C" void kernel_launch(void* const* d_in, const int* in_sizes, int n_in,
                              void* d_out, int out_size, void* d_ws, size_t ws_size,
                              hipStream_t stream) {
    const float* x   = (const float*)d_in[0];
    const int*   ei  = (const int*)d_in[1];
    const int* batch = (const int*)d_in[2];
    const float* W1  = (const float*)d_in[3];
    const float* b1  = (const float*)d_in[4];
    const float* W2  = (const float*)d_in[5];
    const float* b2  = (const float*)d_in[6];
    const float* W3  = (const float*)d_in[7];
    const float* b3  = (const float*)d_in[8];
    const float* Wt1 = (const float*)d_in[9];
    const float* bt1 = (const float*)d_in[10];
    const float* Wt2 = (const float*)d_in[11];
    const float* bt2 = (const float*)d_in[12];
    const float* Wg1 = (const float*)d_in[13];
    const float* bg1 = (const float*)d_in[14];
    const float* Wg2 = (const float*)d_in[15];
    const float* bg2 = (const float*)d_in[16];

    const int N = in_sizes[0];
    const int E = in_sizes[1] / 2;
    const int G = 128;
    const int* src = ei;
    const int* dst = ei + E;
    float* theta_out = (float*)d_out;
    float* bg_out = (float*)d_out + N;

    char* w = (char*)d_ws;
    auto alloc = [&](size_t bytes) -> char* { char* p = w; w += align256(bytes); return p; };
    const int NB = (N + 1023) / 1024;
    int*   deg     = (int*)alloc((size_t)N * 4);
    int*   offs    = (int*)alloc((size_t)(N + 1) * 4);
    int*   pos     = (int*)alloc((size_t)N * 4);
    int*   bsum    = (int*)alloc(1024);
    int*   csr_src = (int*)alloc((size_t)E * 4);
    float* dinv    = (float*)alloc((size_t)N * 4);
    float* bufA    = (float*)alloc((size_t)N * 32 * 4);
    float* bufB    = (float*)alloc((size_t)N * 32 * 4);
    float* gsum    = (float*)alloc((size_t)G * 32 * 4);
    float* gcnt    = (float*)alloc((size_t)G * 4);

    hipMemsetAsync(deg, 0, (size_t)N * 4, stream);
    hipMemsetAsync(gsum, 0, (size_t)G * 32 * 4, stream);
    hipMemsetAsync(gcnt, 0, (size_t)G * 4, stream);

    hist_kernel<<<(E + 255) / 256, 256, 0, stream>>>(dst, deg, E);
    scan1_kernel<<<NB, 256, 0, stream>>>(deg, offs, bsum, dinv, N);
    scan2_kernel<<<1, 256, 0, stream>>>(bsum, NB);
    scan3_kernel<<<(N + 255) / 256, 256, 0, stream>>>(offs, bsum, N, E);
    hipMemcpyAsync(pos, offs, (size_t)N * 4, hipMemcpyDeviceToDevice, stream);
    fill_kernel<<<(E + 255) / 256, 256, 0, stream>>>(src, dst, pos, csr_src, E);

    unsigned gridNF = (unsigned)(((size_t)N * 32 + 255) / 256);  // 32 lanes/node
    unsigned gridNW = (unsigned)(((size_t)N * 64 + 255) / 256);  // 64 lanes/node

    // layer 1
    l1_kernel<<<gridNF, 256, 0, stream>>>(x, W1, dinv, bufB, N);
    agg_kernel<<<gridNW, 256, 0, stream>>>(bufB, offs, csr_src, dinv, b1, bufA, N);
    // layer 2
    gemm_scale_kernel<<<gridNF, 256, 0, stream>>>(bufA, W2, dinv, bufB, N);
    agg_kernel<<<gridNW, 256, 0, stream>>>(bufB, offs, csr_src, dinv, b2, bufA, N);
    // layer 3
    gemm_scale_kernel<<<gridNF, 256, 0, stream>>>(bufA, W3, dinv, bufB, N);
    agg_kernel<<<gridNW, 256, 0, stream>>>(bufB, offs, csr_src, dinv, b3, bufA, N);

    // heads
    theta_kernel<<<gridNF, 256, 0, stream>>>(bufA, Wt1, bt1, Wt2, bt2, theta_out, N);
    pool_kernel<<<(N + 1023) / 1024, 256, 0, stream>>>(bufA, batch, gsum, gcnt, N);
    bg_kernel<<<(G * 32 + 255) / 256, 256, 0, stream>>>(gsum, gcnt, Wg1, bg1, Wg2, bg2, bg_out, G);
}